// Round 7
// baseline (8699.946 us; speedup 1.0000x reference)
//
#include <hip/hip_runtime.h>

// Problem dims
#define BB 128
#define LL 64
#define DD 256
#define HH 512
#define NEGC (-1e9f)

// Persistent grid: 256 blocks x 512 threads, 1 block/CU (82KB LDS forces it).
// XCD x (physical, via HW_REG_XCC_ID + slot claim) owns batches [16x,16x+16).
// GRU weights live in REGISTERS (persistent-RNN): per block u-tile 16, per
// wave 2 units x 4 gate-rows, per lane K-chunks (l+64j)*4 -> 120 VGPR dec,
// 72 VGPR enc. __launch_bounds__(512,2): 2 waves/SIMD -> 256-VGPR budget so
// the weight arrays actually STAY in registers (R6's default cap of 128
// silently spilled them to scratch -> 1.7GB of HBM-backed scratch thrash).
#define NBLK 256
#define NTHR 512

// ws offsets (floats)
#define OFF_DENSE   0            // B*L*D
#define OFF_ENCOUT  2097152      // B*L*H
#define OFF_ENCKEYS 6291456      // B*L*512
#define OFF_PTRKEYS 10485760     // B*L*256
#define OFF_X       12582912     // B*768 [ctx|dec_in]
#define OFF_HB0     12681216     // B*H
#define OFF_HB1     12746752     // B*H
#define OFF_H0      12812288     // B*H
#define OFF_MT      13238272     // Mt2[h=512][a=256] = (W_out^T @ ptr_Wq)
#define OFF_BQ      13369344     // 256
#define OFF_BAR     13369600     // uints: leaf@32i,root@512,gen@544; xcd cnt@640+8x, gen@768+8x, claim@896+8x

__device__ __forceinline__ float fast_tanh(float x) {
  float e = __expf(2.0f * x);
  return 1.0f - 2.0f / (e + 1.0f);
}
__device__ __forceinline__ float sigmoidf_(float x) {
  return 1.0f / (1.0f + __expf(-x));
}
__device__ __forceinline__ float wsum(float v) {
#pragma unroll
  for (int o = 32; o > 0; o >>= 1) v += __shfl_xor(v, o);
  return v;
}
__device__ __forceinline__ float dot4(float4 a, float4 b) {
  return fmaf(a.x, b.x, fmaf(a.y, b.y, fmaf(a.z, b.z, a.w * b.w)));
}

struct MegaArgs {
  const float* inputs; const int* lengths; const int* targets;
  const float* W_in; const float* b_in;
  const float* enc_Wi; const float* enc_Wh; const float* enc_bi; const float* enc_bh;
  const float* dec_Wi; const float* dec_Wh; const float* dec_bi; const float* dec_bh;
  const float* s2s_Wq; const float* s2s_Wk; const float* s2s_v;
  const float* W_out; const float* b_out;
  const float* ptr_Wq; const float* ptr_Wk; const float* ptr_v;
  float* ws; float* logits; float* preds;
};

// XCD-local barrier (R5/R6-proven): coherent counter + vL1-only buffer_inv.
__device__ __forceinline__ void xbar(unsigned* bar, int xcd) {
  __syncthreads();
  if (threadIdx.x == 0) {
    unsigned* cnt = bar + 640 + xcd * 8;
    unsigned* gen = bar + 768 + xcd * 8;
    unsigned g = __hip_atomic_load(gen, __ATOMIC_RELAXED, __HIP_MEMORY_SCOPE_AGENT);
    unsigned v = __hip_atomic_fetch_add(cnt, 1u, __ATOMIC_RELAXED, __HIP_MEMORY_SCOPE_AGENT);
    if ((v & 31u) == 31u) {
      __hip_atomic_store(gen, g + 1u, __ATOMIC_RELAXED, __HIP_MEMORY_SCOPE_AGENT);
    } else {
      while (__hip_atomic_load(gen, __ATOMIC_RELAXED, __HIP_MEMORY_SCOPE_AGENT) == g)
        __builtin_amdgcn_s_sleep(1);
    }
    asm volatile("buffer_inv" ::: "memory");
  }
  __syncthreads();
}

// Grid-wide heavy barrier (used once post-setup): full fence pair.
__device__ __forceinline__ void heavybar(unsigned* bar, int blk) {
  __syncthreads();
  if (threadIdx.x == 0) {
    __threadfence();
    unsigned* leaf = bar + ((blk >> 4) << 5);
    unsigned* root = bar + 512;
    unsigned* gen  = bar + 544;
    unsigned g = __hip_atomic_load(gen, __ATOMIC_RELAXED, __HIP_MEMORY_SCOPE_AGENT);
    unsigned v = __hip_atomic_fetch_add(leaf, 1u, __ATOMIC_RELAXED, __HIP_MEMORY_SCOPE_AGENT);
    if ((v & 15u) == 15u) {
      unsigned r = __hip_atomic_fetch_add(root, 1u, __ATOMIC_RELAXED, __HIP_MEMORY_SCOPE_AGENT);
      if ((r & 15u) == 15u)
        __hip_atomic_store(gen, g + 1u, __ATOMIC_RELAXED, __HIP_MEMORY_SCOPE_AGENT);
    }
    while (__hip_atomic_load(gen, __ATOMIC_RELAXED, __HIP_MEMORY_SCOPE_AGENT) == g)
      __builtin_amdgcn_s_sleep(1);
    __threadfence();
  }
  __syncthreads();
}

struct SMem {
  union {
    struct { float xs[16 * 768]; } e;                                  // encoder x [dense|h]
    struct { float xs[16 * 1280]; } p2;                                // dec x [xbuf|h] 80KB
    struct { float sh[512]; float qq[768]; float pp[512]; float sl[64]; float wl[64]; } p1;
    struct { float s[32 * 256]; } pk;
    struct { float s[16 * 512]; } ek;
  };
  float pad_[160];    // push LDS >80KB -> exactly 1 block/CU
  unsigned xcd, sid;
};

__global__ __launch_bounds__(NTHR, 2) void mega(MegaArgs a) {
  const int blk = blockIdx.x;
  const int tid = threadIdx.x;
  float* ws = a.ws;
  float* dense    = ws + OFF_DENSE;
  float* enc_out  = ws + OFF_ENCOUT;
  float* enc_keys = ws + OFF_ENCKEYS;
  float* ptr_keys = ws + OFF_PTRKEYS;
  float* xbuf     = ws + OFF_X;
  float* hbuf[2]  = { ws + OFF_HB0, ws + OFF_HB1 };
  float* h0buf    = ws + OFF_H0;
  float* Mt2      = ws + OFF_MT;
  float* bqv      = ws + OFF_BQ;
  unsigned* bar   = (unsigned*)(ws + OFF_BAR);

  __shared__ SMem sm;

  // ---- physical XCD + slot claim (R5-proven) ----
  if (tid == 0) {
    unsigned x;
    asm volatile("s_getreg_b32 %0, hwreg(HW_REG_XCC_ID)" : "=s"(x));
    x &= 7u;
    unsigned s = __hip_atomic_fetch_add(bar + 896 + x * 8, 1u,
                                        __ATOMIC_RELAXED, __HIP_MEMORY_SCOPE_AGENT);
    sm.xcd = x; sm.sid = s & 31u;
  }
  __syncthreads();
  const int xcd = sm.xcd, sid = sm.sid;
  const int b0x = xcd * 16;
  const int w = tid >> 6, l = tid & 63;
  const int u0 = sid * 16;
  const int ua = u0 + 2 * w;          // this wave's unit pair (ua, ua+1)

  unsigned long long alive = ~0ull;   // pointer mask (pointer blocks, sid>=16)

  // ---------------- S1: dense (local), Mt2/bqv (global), zero hb0 ----------------
  for (int idx = sid * NTHR + tid; idx < 16 * 64 * 256; idx += 32 * NTHR) {
    int row = idx >> 8, d = idx & 255;
    int g = b0x * 64 + row;
    dense[g * 256 + d] = fmaf(a.inputs[g * 2], a.W_in[d * 2],
                         fmaf(a.inputs[g * 2 + 1], a.W_in[d * 2 + 1], a.b_in[d]));
  }
  if (tid < 256) {   // Mt2 rows 2blk, 2blk+1
    int h1 = blk * 2;
    float acc1 = 0.f, acc2 = 0.f;
    for (int d = 0; d < 256; ++d) {
      float p = a.ptr_Wq[d * 256 + tid];
      acc1 = fmaf(a.W_out[d * 512 + h1], p, acc1);
      acc2 = fmaf(a.W_out[d * 512 + h1 + 1], p, acc2);
    }
    Mt2[h1 * 256 + tid] = acc1;
    Mt2[(h1 + 1) * 256 + tid] = acc2;
  }
  if (blk == 0 && tid < 256) {
    float acc = 0.f;
    for (int d = 0; d < 256; ++d) acc = fmaf(a.b_out[d], a.ptr_Wq[d * 256 + tid], acc);
    bqv[tid] = acc;
  }
  for (int idx = sid * NTHR + tid; idx < 16 * 512; idx += 32 * NTHR)
    hbuf[0][b0x * 512 + idx] = 0.f;
  heavybar(bar, blk);

  // ---------------- PK: ptr_keys (XCD-local, 32 rows/block) ----------------
  {
    const int r0 = xcd * 1024 + sid * 32;
    for (int idx = tid; idx < 32 * 256; idx += NTHR) sm.pk.s[idx] = dense[r0 * 256 + idx];
    __syncthreads();
    const int col = tid & 255, rg = tid >> 8;
    float acc[16];
#pragma unroll
    for (int ri = 0; ri < 16; ++ri) acc[ri] = 0.f;
    const float* srow = sm.pk.s + rg * 16 * 256;
    for (int d = 0; d < 256; ++d) {
      float wv = a.ptr_Wk[d * 256 + col];
#pragma unroll
      for (int ri = 0; ri < 16; ++ri) acc[ri] = fmaf(srow[ri * 256 + d], wv, acc[ri]);
    }
#pragma unroll
    for (int ri = 0; ri < 16; ++ri)
      ptr_keys[(r0 + rg * 16 + ri) * 256 + col] = acc[ri];
  }
  xbar(bar, xcd);

  // ---------------- encoder: register-stationary weights ----------------
  {
    float4 ewr[2][3], ewz[2][3], ewin[2], ewhn[2][2];
    float eb[2][4];
#pragma unroll
    for (int du = 0; du < 2; ++du) {
      const int u = ua + du;
      ewr[du][0] = *(const float4*)(a.enc_Wi + (u) * 256 + l * 4);
      ewr[du][1] = *(const float4*)(a.enc_Wh + (u) * 512 + l * 4);
      ewr[du][2] = *(const float4*)(a.enc_Wh + (u) * 512 + (l + 64) * 4);
      ewz[du][0] = *(const float4*)(a.enc_Wi + (512 + u) * 256 + l * 4);
      ewz[du][1] = *(const float4*)(a.enc_Wh + (512 + u) * 512 + l * 4);
      ewz[du][2] = *(const float4*)(a.enc_Wh + (512 + u) * 512 + (l + 64) * 4);
      ewin[du]    = *(const float4*)(a.enc_Wi + (1024 + u) * 256 + l * 4);
      ewhn[du][0] = *(const float4*)(a.enc_Wh + (1024 + u) * 512 + l * 4);
      ewhn[du][1] = *(const float4*)(a.enc_Wh + (1024 + u) * 512 + (l + 64) * 4);
      eb[du][0] = a.enc_bi[u] + a.enc_bh[u];
      eb[du][1] = a.enc_bi[512 + u] + a.enc_bh[512 + u];
      eb[du][2] = a.enc_bi[1024 + u];
      eb[du][3] = a.enc_bh[1024 + u];
    }
#pragma unroll 1
    for (int t = 0; t < 64; ++t) {
      const float* hin = hbuf[t & 1];
      float* hout = hbuf[(t + 1) & 1];
      for (int idx = tid; idx < 16 * 192; idx += NTHR) {   // x = [dense_t(256)|h(512)]
        int bl = idx / 192, kk = idx - bl * 192;
        float4 v = (kk < 64)
            ? *(const float4*)&dense[((b0x + bl) * 64 + t) * 256 + kk * 4]
            : *(const float4*)&hin[(b0x + bl) * 512 + (kk - 64) * 4];
        *(float4*)&sm.e.xs[bl * 768 + kk * 4] = v;
      }
      __syncthreads();
#pragma unroll 2
      for (int b = 0; b < 16; ++b) {
        const float* xr = sm.e.xs + b * 768;
        float4 xv0 = *(const float4*)(xr + l * 4);
        float4 xv1 = *(const float4*)(xr + 256 + l * 4);
        float4 xv2 = *(const float4*)(xr + 512 + l * 4);
        float aR0 = dot4(ewr[0][0], xv0) + dot4(ewr[0][1], xv1) + dot4(ewr[0][2], xv2);
        float aZ0 = dot4(ewz[0][0], xv0) + dot4(ewz[0][1], xv1) + dot4(ewz[0][2], xv2);
        float aI0 = dot4(ewin[0], xv0);
        float aH0 = dot4(ewhn[0][0], xv1) + dot4(ewhn[0][1], xv2);
        float aR1 = dot4(ewr[1][0], xv0) + dot4(ewr[1][1], xv1) + dot4(ewr[1][2], xv2);
        float aZ1 = dot4(ewz[1][0], xv0) + dot4(ewz[1][1], xv1) + dot4(ewz[1][2], xv2);
        float aI1 = dot4(ewin[1], xv0);
        float aH1 = dot4(ewhn[1][0], xv1) + dot4(ewhn[1][1], xv2);
        aR0 = wsum(aR0); aZ0 = wsum(aZ0); aI0 = wsum(aI0); aH0 = wsum(aH0);
        aR1 = wsum(aR1); aZ1 = wsum(aZ1); aI1 = wsum(aI1); aH1 = wsum(aH1);
        const int gb = b0x + b;
        float r0 = sigmoidf_(aR0 + eb[0][0]);
        float z0 = sigmoidf_(aZ0 + eb[0][1]);
        float n0 = fast_tanh(aI0 + eb[0][2] + r0 * (aH0 + eb[0][3]));
        float h0v = (1.f - z0) * n0 + z0 * xr[256 + ua];
        float r1 = sigmoidf_(aR1 + eb[1][1 - 1]);
        float z1 = sigmoidf_(aZ1 + eb[1][1]);
        float n1 = fast_tanh(aI1 + eb[1][2] + r1 * (aH1 + eb[1][3]));
        float h1v = (1.f - z1) * n1 + z1 * xr[256 + ua + 1];
        if (l == 0) {
          int lenb = a.lengths[gb];
          float2 hv = make_float2(h0v, h1v);
          *(float2*)&hout[gb * 512 + ua] = hv;
          float2 ev = (t < lenb) ? hv : make_float2(0.f, 0.f);
          *(float2*)&enc_out[(gb * 64 + t) * 512 + ua] = ev;
          if (t == lenb - 1) *(float2*)&h0buf[gb * 512 + ua] = hv;
        }
      }
      xbar(bar, xcd);
    }
  }

  // ---------------- EK: enc_keys (XCD-local) ----------------
#pragma unroll 1
  for (int rep = 0; rep < 2; ++rep) {
    const int r0 = xcd * 1024 + sid * 32 + rep * 16;
    for (int idx = tid; idx < 16 * 512; idx += NTHR) sm.ek.s[idx] = enc_out[r0 * 512 + idx];
    __syncthreads();
    float acc[16];
#pragma unroll
    for (int ri = 0; ri < 16; ++ri) acc[ri] = 0.f;
    for (int h = 0; h < 512; ++h) {
      float wv = a.s2s_Wk[h * 512 + tid];
#pragma unroll
      for (int ri = 0; ri < 16; ++ri) acc[ri] = fmaf(sm.ek.s[ri * 512 + h], wv, acc[ri]);
    }
#pragma unroll
    for (int ri = 0; ri < 16; ++ri) enc_keys[(r0 + ri) * 512 + tid] = acc[ri];
    __syncthreads();
  }
  xbar(bar, xcd);

  // ---------------- decoder persistent registers ----------------
  float4 dwr[2][5], dwz[2][5], dwin[2][3], dwhn[2][2];   // 120 VGPR gate weights
  float db[2][4];
#pragma unroll
  for (int du = 0; du < 2; ++du) {
    const int u = ua + du;
#pragma unroll
    for (int j = 0; j < 3; ++j) {
      dwr[du][j]  = *(const float4*)(a.dec_Wi + (u) * 768 + (l + 64 * j) * 4);
      dwz[du][j]  = *(const float4*)(a.dec_Wi + (512 + u) * 768 + (l + 64 * j) * 4);
      dwin[du][j] = *(const float4*)(a.dec_Wi + (1024 + u) * 768 + (l + 64 * j) * 4);
    }
    dwr[du][3] = *(const float4*)(a.dec_Wh + (u) * 512 + l * 4);
    dwr[du][4] = *(const float4*)(a.dec_Wh + (u) * 512 + (l + 64) * 4);
    dwz[du][3] = *(const float4*)(a.dec_Wh + (512 + u) * 512 + l * 4);
    dwz[du][4] = *(const float4*)(a.dec_Wh + (512 + u) * 512 + (l + 64) * 4);
    dwhn[du][0] = *(const float4*)(a.dec_Wh + (1024 + u) * 512 + l * 4);
    dwhn[du][1] = *(const float4*)(a.dec_Wh + (1024 + u) * 512 + (l + 64) * 4);
    db[du][0] = a.dec_bi[u] + a.dec_bh[u];
    db[du][1] = a.dec_bi[512 + u] + a.dec_bh[512 + u];
    db[du][2] = a.dec_bi[1024 + u];
    db[du][3] = a.dec_bh[1024 + u];
  }
  float eo[64];   // s2s blocks: own batch's enc_out column h=tid
  if (sid < 16) {
    const int b = b0x + sid;
#pragma unroll
    for (int l2 = 0; l2 < 64; ++l2) eo[l2] = enc_out[(b * 64 + l2) * 512 + tid];
  }

  // A1-s2s: q-GEMV + attention + context -> xbuf (blocks sid<16)
  auto s2sphase = [&](int i, const float* hsrc) {
    const int b = b0x + sid;
    sm.p1.sh[tid] = hsrc[b * 512 + tid];
    __syncthreads();
    {
      float acc = 0.f;
#pragma unroll 4
      for (int k = 0; k < 512; k += 4) {
        float4 hv = *(const float4*)(sm.p1.sh + k);
        acc = fmaf(a.s2s_Wq[(k) * 512 + tid], hv.x,
              fmaf(a.s2s_Wq[(k + 1) * 512 + tid], hv.y,
              fmaf(a.s2s_Wq[(k + 2) * 512 + tid], hv.z,
              fmaf(a.s2s_Wq[(k + 3) * 512 + tid], hv.w, acc))));
      }
      sm.p1.qq[tid] = acc;
    }
    __syncthreads();
    const int lenb = a.lengths[b];
    float rq[8], sv[8];
#pragma unroll
    for (int c = 0; c < 8; ++c) { rq[c] = sm.p1.qq[c * 64 + l]; sv[c] = a.s2s_v[c * 64 + l]; }
#pragma unroll
    for (int li = 0; li < 8; ++li) {
      int lr = w * 8 + li;
      float acc = 0.f;
#pragma unroll
      for (int c = 0; c < 8; ++c)
        acc = fmaf(fast_tanh(rq[c] + enc_keys[(b * 64 + lr) * 512 + c * 64 + l]), sv[c], acc);
      acc = wsum(acc);
      if (l == 0) sm.p1.sl[lr] = ((i < lenb) && (lr < lenb)) ? acc : NEGC;
    }
    __syncthreads();
    if (tid < 64) {
      float v = sm.p1.sl[tid];
      float m = v;
#pragma unroll
      for (int off = 32; off > 0; off >>= 1) m = fmaxf(m, __shfl_xor(m, off));
      float e = __expf(v - m);
      float s = e;
#pragma unroll
      for (int off = 32; off > 0; off >>= 1) s += __shfl_xor(s, off);
      sm.p1.wl[tid] = e / s;
    }
    __syncthreads();
    {
      float c = 0.f;
#pragma unroll
      for (int l2 = 0; l2 < 64; ++l2) c = fmaf(sm.p1.wl[l2], eo[l2], c);
      xbuf[b * 768 + tid] = c;
    }
    if (tid < 256) {
      int di = (i == 0) ? 0 : a.targets[b * 64 + i - 1];
      xbuf[b * 768 + 512 + tid] = dense[(b * 64 + di) * 256 + tid];
    }
  };

  // A1-ptr: pq-GEMV + pointer logits j=i-1 (blocks sid>=16)
  auto ptrphase = [&](int i, const float* hsrc) {
    if (i == 0) return;
    const int b = b0x + (sid - 16);
    sm.p1.sh[tid] = hsrc[b * 512 + tid];
    __syncthreads();
    {
      const int o = tid & 255, hf = tid >> 8;
      float acc = 0.f;
      const int k0 = hf * 256;
#pragma unroll 4
      for (int k = k0; k < k0 + 256; k += 4) {
        float4 hv = *(const float4*)(sm.p1.sh + k);
        acc = fmaf(Mt2[(k) * 256 + o], hv.x,
              fmaf(Mt2[(k + 1) * 256 + o], hv.y,
              fmaf(Mt2[(k + 2) * 256 + o], hv.z,
              fmaf(Mt2[(k + 3) * 256 + o], hv.w, acc))));
      }
      sm.p1.pp[hf * 256 + o] = acc;
    }
    __syncthreads();
    if (tid < 256) sm.p1.qq[tid] = sm.p1.pp[tid] + sm.p1.pp[256 + tid] + bqv[tid];
    __syncthreads();
    const int j = i - 1;
    const int lenb = a.lengths[b];
    float rq[4], pv[4];
#pragma unroll
    for (int c = 0; c < 4; ++c) { rq[c] = sm.p1.qq[c * 64 + l]; pv[c] = a.ptr_v[c * 64 + l]; }
#pragma unroll
    for (int li = 0; li < 8; ++li) {
      int lr = w * 8 + li;
      float acc = 0.f;
#pragma unroll
      for (int c = 0; c < 4; ++c)
        acc = fmaf(fast_tanh(rq[c] + ptr_keys[(b * 64 + lr) * 256 + c * 64 + l]), pv[c], acc);
      acc = wsum(acc);
      if (l == 0) sm.p1.sl[lr] = acc;
    }
    __syncthreads();
    if (tid < 64) {
      int lr = tid;
      bool pm = (j < lenb) && (lr < lenb) && ((alive >> lr) & 1ull);
      float v = pm ? sm.p1.sl[lr] : NEGC;
      a.logits[(b * 64 + j) * 64 + lr] = v;
      float bv = v; int bidx = lr;
#pragma unroll
      for (int off = 32; off > 0; off >>= 1) {
        float ov = __shfl_xor(bv, off);
        int oi = __shfl_xor(bidx, off);
        if (ov > bv || (ov == bv && oi < bidx)) { bv = ov; bidx = oi; }
      }
      if (lr == 0) a.preds[b * 64 + j] = (float)bidx;
    }
    alive &= ~(1ull << (unsigned)a.targets[b * 64 + j]);
    __syncthreads();
  };

  // ---------------- decoder: 64 x { P1(s2s || ptr), P2(gates) } ----------------
#pragma unroll 1
  for (int i = 0; i < 64; ++i) {
    const float* hsrc = (i == 0) ? h0buf : hbuf[i & 1];
    if (sid < 16) s2sphase(i, hsrc); else ptrphase(i, hsrc);
    xbar(bar, xcd);
    {   // P2: register-weight gates, x = [xbuf(768)|h(512)]
      const float* hin = hsrc;
      for (int idx = tid; idx < 16 * 320; idx += NTHR) {
        int bl = idx / 320, kk = idx - bl * 320;
        float4 v = (kk < 192) ? *(const float4*)&xbuf[(b0x + bl) * 768 + kk * 4]
                              : *(const float4*)&hin[(b0x + bl) * 512 + (kk - 192) * 4];
        *(float4*)&sm.p2.xs[bl * 1280 + kk * 4] = v;
      }
      __syncthreads();
#pragma unroll 2
      for (int b = 0; b < 16; ++b) {
        const float* xr = sm.p2.xs + b * 1280;
        float4 xv0 = *(const float4*)(xr + l * 4);
        float4 xv1 = *(const float4*)(xr + 256 + l * 4);
        float4 xv2 = *(const float4*)(xr + 512 + l * 4);
        float4 xv3 = *(const float4*)(xr + 768 + l * 4);
        float4 xv4 = *(const float4*)(xr + 1024 + l * 4);
        float aR0 = dot4(dwr[0][0], xv0) + dot4(dwr[0][1], xv1) + dot4(dwr[0][2], xv2)
                  + dot4(dwr[0][3], xv3) + dot4(dwr[0][4], xv4);
        float aZ0 = dot4(dwz[0][0], xv0) + dot4(dwz[0][1], xv1) + dot4(dwz[0][2], xv2)
                  + dot4(dwz[0][3], xv3) + dot4(dwz[0][4], xv4);
        float aI0 = dot4(dwin[0][0], xv0) + dot4(dwin[0][1], xv1) + dot4(dwin[0][2], xv2);
        float aH0 = dot4(dwhn[0][0], xv3) + dot4(dwhn[0][1], xv4);
        float aR1 = dot4(dwr[1][0], xv0) + dot4(dwr[1][1], xv1) + dot4(dwr[1][2], xv2)
                  + dot4(dwr[1][3], xv3) + dot4(dwr[1][4], xv4);
        float aZ1 = dot4(dwz[1][0], xv0) + dot4(dwz[1][1], xv1) + dot4(dwz[1][2], xv2)
                  + dot4(dwz[1][3], xv3) + dot4(dwz[1][4], xv4);
        float aI1 = dot4(dwin[1][0], xv0) + dot4(dwin[1][1], xv1) + dot4(dwin[1][2], xv2);
        float aH1 = dot4(dwhn[1][0], xv3) + dot4(dwhn[1][1], xv4);
        aR0 = wsum(aR0); aZ0 = wsum(aZ0); aI0 = wsum(aI0); aH0 = wsum(aH0);
        aR1 = wsum(aR1); aZ1 = wsum(aZ1); aI1 = wsum(aI1); aH1 = wsum(aH1);
        float r0 = sigmoidf_(aR0 + db[0][0]);
        float z0 = sigmoidf_(aZ0 + db[0][1]);
        float n0 = fast_tanh(aI0 + db[0][2] + r0 * (aH0 + db[0][3]));
        float hv0 = (1.f - z0) * n0 + z0 * xr[768 + ua];
        float r1 = sigmoidf_(aR1 + db[1][0]);
        float z1 = sigmoidf_(aZ1 + db[1][1]);
        float n1 = fast_tanh(aI1 + db[1][2] + r1 * (aH1 + db[1][3]));
        float hv1 = (1.f - z1) * n1 + z1 * xr[768 + ua + 1];
        if (l == 0)
          *(float2*)&hbuf[(i + 1) & 1][(b0x + b) * 512 + ua] = make_float2(hv0, hv1);
      }
    }
    xbar(bar, xcd);
  }
  if (sid >= 16) ptrphase(64, hbuf[0]);   // final pointer row j=63 (h_64 in hbuf[0])
}

extern "C" void kernel_launch(void* const* d_in, const int* in_sizes, int n_in,
                              void* d_out, int out_size, void* d_ws, size_t ws_size,
                              hipStream_t stream) {
  (void)in_sizes; (void)n_in; (void)out_size; (void)ws_size;
  MegaArgs ma;
  ma.inputs  = (const float*)d_in[0];
  ma.lengths = (const int*)d_in[1];
  ma.targets = (const int*)d_in[2];
  ma.W_in    = (const float*)d_in[3];
  ma.b_in    = (const float*)d_in[4];
  ma.enc_Wi  = (const float*)d_in[5];
  ma.enc_Wh  = (const float*)d_in[6];
  ma.enc_bi  = (const float*)d_in[7];
  ma.enc_bh  = (const float*)d_in[8];
  ma.dec_Wi  = (const float*)d_in[9];
  ma.dec_Wh  = (const float*)d_in[10];
  ma.dec_bi  = (const float*)d_in[11];
  ma.dec_bh  = (const float*)d_in[12];
  ma.s2s_Wq  = (const float*)d_in[13];
  ma.s2s_Wk  = (const float*)d_in[14];
  ma.s2s_v   = (const float*)d_in[15];
  ma.W_out   = (const float*)d_in[16];
  ma.b_out   = (const float*)d_in[17];
  ma.ptr_Wq  = (const float*)d_in[18];
  ma.ptr_Wk  = (const float*)d_in[19];
  ma.ptr_v   = (const float*)d_in[20];
  ma.ws     = (float*)d_ws;
  ma.logits = (float*)d_out;
  ma.preds  = (float*)d_out + BB * LL * LL;

  hipMemsetAsync((float*)d_ws + OFF_BAR, 0, 8192, stream);

  void* kp[] = { &ma };
  hipLaunchCooperativeKernel(reinterpret_cast<const void*>(&mega),
                             dim3(NBLK), dim3(NTHR), kp, 0, stream);
}

// Round 8
// 8486.147 us; speedup vs baseline: 1.0252x; 1.0252x over previous
//
#include <hip/hip_runtime.h>

// Problem dims
#define BB 128
#define LL 64
#define DD 256
#define HH 512
#define NEGC (-1e9f)

// Persistent grid: 256 blocks x 512 threads, 1 block/CU (82KB LDS forces it).
// XCD x (physical, via HW_REG_XCC_ID + slot claim) owns batches [16x,16x+16).
// GRU weights live in REGISTERS (persistent-RNN). __launch_bounds__(512,1):
// 1 block/CU -> 8 waves/CU -> 256-VGPR budget. (R7's (512,2) was interpreted
// as 2 blocks/CU -> 128-VGPR cap -> weights silently re-loaded/spilled.)
// kr[64] union: s2s blocks = enc_out column (context), ptr blocks = hoisted
// ptr_keys. Step-invariant streams left in L2: s2s_Wq(1MB)+Mt2(0.5)+enc_keys
// (2.1MB/XCD) = ~3.6MB < 4MB L2 -> resident after first touch.
#define NBLK 256
#define NTHR 512

// ws offsets (floats)
#define OFF_DENSE   0            // B*L*D
#define OFF_ENCOUT  2097152      // B*L*H
#define OFF_ENCKEYS 6291456      // B*L*512
#define OFF_PTRKEYS 10485760     // B*L*256
#define OFF_X       12582912     // B*768 [ctx|dec_in]
#define OFF_HB0     12681216     // B*H
#define OFF_HB1     12746752     // B*H
#define OFF_H0      12812288     // B*H
#define OFF_MT      13238272     // Mt2[h=512][a=256] = (W_out^T @ ptr_Wq)
#define OFF_BQ      13369344     // 256
#define OFF_BAR     13369600     // uints: leaf@32i,root@512,gen@544; xcd cnt@640+8x, gen@768+8x, claim@896+8x

__device__ __forceinline__ float fast_tanh(float x) {
  float e = __expf(2.0f * x);
  return 1.0f - 2.0f / (e + 1.0f);
}
__device__ __forceinline__ float sigmoidf_(float x) {
  return 1.0f / (1.0f + __expf(-x));
}
__device__ __forceinline__ float wsum(float v) {
#pragma unroll
  for (int o = 32; o > 0; o >>= 1) v += __shfl_xor(v, o);
  return v;
}
__device__ __forceinline__ float dot4(float4 a, float4 b) {
  return fmaf(a.x, b.x, fmaf(a.y, b.y, fmaf(a.z, b.z, a.w * b.w)));
}

struct MegaArgs {
  const float* inputs; const int* lengths; const int* targets;
  const float* W_in; const float* b_in;
  const float* enc_Wi; const float* enc_Wh; const float* enc_bi; const float* enc_bh;
  const float* dec_Wi; const float* dec_Wh; const float* dec_bi; const float* dec_bh;
  const float* s2s_Wq; const float* s2s_Wk; const float* s2s_v;
  const float* W_out; const float* b_out;
  const float* ptr_Wq; const float* ptr_Wk; const float* ptr_v;
  float* ws; float* logits; float* preds;
};

// XCD-local barrier (R5-R7-proven): coherent counter + vL1-only buffer_inv.
__device__ __forceinline__ void xbar(unsigned* bar, int xcd) {
  __syncthreads();
  if (threadIdx.x == 0) {
    unsigned* cnt = bar + 640 + xcd * 8;
    unsigned* gen = bar + 768 + xcd * 8;
    unsigned g = __hip_atomic_load(gen, __ATOMIC_RELAXED, __HIP_MEMORY_SCOPE_AGENT);
    unsigned v = __hip_atomic_fetch_add(cnt, 1u, __ATOMIC_RELAXED, __HIP_MEMORY_SCOPE_AGENT);
    if ((v & 31u) == 31u) {
      __hip_atomic_store(gen, g + 1u, __ATOMIC_RELAXED, __HIP_MEMORY_SCOPE_AGENT);
    } else {
      while (__hip_atomic_load(gen, __ATOMIC_RELAXED, __HIP_MEMORY_SCOPE_AGENT) == g)
        __builtin_amdgcn_s_sleep(1);
    }
    asm volatile("buffer_inv" ::: "memory");
  }
  __syncthreads();
}

// Grid-wide heavy barrier (used once post-setup): full fence pair.
__device__ __forceinline__ void heavybar(unsigned* bar, int blk) {
  __syncthreads();
  if (threadIdx.x == 0) {
    __threadfence();
    unsigned* leaf = bar + ((blk >> 4) << 5);
    unsigned* root = bar + 512;
    unsigned* gen  = bar + 544;
    unsigned g = __hip_atomic_load(gen, __ATOMIC_RELAXED, __HIP_MEMORY_SCOPE_AGENT);
    unsigned v = __hip_atomic_fetch_add(leaf, 1u, __ATOMIC_RELAXED, __HIP_MEMORY_SCOPE_AGENT);
    if ((v & 15u) == 15u) {
      unsigned r = __hip_atomic_fetch_add(root, 1u, __ATOMIC_RELAXED, __HIP_MEMORY_SCOPE_AGENT);
      if ((r & 15u) == 15u)
        __hip_atomic_store(gen, g + 1u, __ATOMIC_RELAXED, __HIP_MEMORY_SCOPE_AGENT);
    }
    while (__hip_atomic_load(gen, __ATOMIC_RELAXED, __HIP_MEMORY_SCOPE_AGENT) == g)
      __builtin_amdgcn_s_sleep(1);
    __threadfence();
  }
  __syncthreads();
}

struct SMem {
  union {
    struct { float xs[16 * 768]; } e;                                  // encoder x [dense|h]
    struct { float xs[16 * 1280]; } p2;                                // dec x [xbuf|h] 80KB
    struct { float sh[512]; float qq[768]; float pp[512]; float sl[64]; float wl[64]; } p1;
    struct { float s[32 * 256]; } pk;
    struct { float s[16 * 512]; } ek;
  };
  float pad_[160];    // push LDS >80KB -> exactly 1 block/CU
  unsigned xcd, sid;
};

__global__ __launch_bounds__(NTHR, 1) void mega(MegaArgs a) {
  const int blk = blockIdx.x;
  const int tid = threadIdx.x;
  float* ws = a.ws;
  float* dense    = ws + OFF_DENSE;
  float* enc_out  = ws + OFF_ENCOUT;
  float* enc_keys = ws + OFF_ENCKEYS;
  float* ptr_keys = ws + OFF_PTRKEYS;
  float* xbuf     = ws + OFF_X;
  float* hbuf[2]  = { ws + OFF_HB0, ws + OFF_HB1 };
  float* h0buf    = ws + OFF_H0;
  float* Mt2      = ws + OFF_MT;
  float* bqv      = ws + OFF_BQ;
  unsigned* bar   = (unsigned*)(ws + OFF_BAR);

  __shared__ SMem sm;

  // ---- physical XCD + slot claim (R5-proven) ----
  if (tid == 0) {
    unsigned x;
    asm volatile("s_getreg_b32 %0, hwreg(HW_REG_XCC_ID)" : "=s"(x));
    x &= 7u;
    unsigned s = __hip_atomic_fetch_add(bar + 896 + x * 8, 1u,
                                        __ATOMIC_RELAXED, __HIP_MEMORY_SCOPE_AGENT);
    sm.xcd = x; sm.sid = s & 31u;
  }
  __syncthreads();
  const int xcd = sm.xcd, sid = sm.sid;
  const int b0x = xcd * 16;
  const int w = tid >> 6, l = tid & 63;
  const int u0 = sid * 16;
  const int ua = u0 + 2 * w;          // this wave's unit pair (ua, ua+1)

  unsigned long long alive = ~0ull;   // pointer mask (pointer blocks, sid>=16)

  // ---------------- S1: dense (local), Mt2/bqv (global), zero hb0 ----------------
  for (int idx = sid * NTHR + tid; idx < 16 * 64 * 256; idx += 32 * NTHR) {
    int row = idx >> 8, d = idx & 255;
    int g = b0x * 64 + row;
    dense[g * 256 + d] = fmaf(a.inputs[g * 2], a.W_in[d * 2],
                         fmaf(a.inputs[g * 2 + 1], a.W_in[d * 2 + 1], a.b_in[d]));
  }
  if (tid < 256) {   // Mt2 rows 2blk, 2blk+1
    int h1 = blk * 2;
    float acc1 = 0.f, acc2 = 0.f;
    for (int d = 0; d < 256; ++d) {
      float p = a.ptr_Wq[d * 256 + tid];
      acc1 = fmaf(a.W_out[d * 512 + h1], p, acc1);
      acc2 = fmaf(a.W_out[d * 512 + h1 + 1], p, acc2);
    }
    Mt2[h1 * 256 + tid] = acc1;
    Mt2[(h1 + 1) * 256 + tid] = acc2;
  }
  if (blk == 0 && tid < 256) {
    float acc = 0.f;
    for (int d = 0; d < 256; ++d) acc = fmaf(a.b_out[d], a.ptr_Wq[d * 256 + tid], acc);
    bqv[tid] = acc;
  }
  for (int idx = sid * NTHR + tid; idx < 16 * 512; idx += 32 * NTHR)
    hbuf[0][b0x * 512 + idx] = 0.f;
  heavybar(bar, blk);

  // ---------------- PK: ptr_keys (XCD-local, 32 rows/block) ----------------
  {
    const int r0 = xcd * 1024 + sid * 32;
    for (int idx = tid; idx < 32 * 256; idx += NTHR) sm.pk.s[idx] = dense[r0 * 256 + idx];
    __syncthreads();
    const int col = tid & 255, rg = tid >> 8;
    float acc[16];
#pragma unroll
    for (int ri = 0; ri < 16; ++ri) acc[ri] = 0.f;
    const float* srow = sm.pk.s + rg * 16 * 256;
    for (int d = 0; d < 256; ++d) {
      float wv = a.ptr_Wk[d * 256 + col];
#pragma unroll
      for (int ri = 0; ri < 16; ++ri) acc[ri] = fmaf(srow[ri * 256 + d], wv, acc[ri]);
    }
#pragma unroll
    for (int ri = 0; ri < 16; ++ri)
      ptr_keys[(r0 + rg * 16 + ri) * 256 + col] = acc[ri];
  }
  xbar(bar, xcd);

  // ---------------- encoder: register-stationary weights ----------------
  {
    float4 ewr[2][3], ewz[2][3], ewin[2], ewhn[2][2];
    float eb[2][4];
#pragma unroll
    for (int du = 0; du < 2; ++du) {
      const int u = ua + du;
      ewr[du][0] = *(const float4*)(a.enc_Wi + (u) * 256 + l * 4);
      ewr[du][1] = *(const float4*)(a.enc_Wh + (u) * 512 + l * 4);
      ewr[du][2] = *(const float4*)(a.enc_Wh + (u) * 512 + (l + 64) * 4);
      ewz[du][0] = *(const float4*)(a.enc_Wi + (512 + u) * 256 + l * 4);
      ewz[du][1] = *(const float4*)(a.enc_Wh + (512 + u) * 512 + l * 4);
      ewz[du][2] = *(const float4*)(a.enc_Wh + (512 + u) * 512 + (l + 64) * 4);
      ewin[du]    = *(const float4*)(a.enc_Wi + (1024 + u) * 256 + l * 4);
      ewhn[du][0] = *(const float4*)(a.enc_Wh + (1024 + u) * 512 + l * 4);
      ewhn[du][1] = *(const float4*)(a.enc_Wh + (1024 + u) * 512 + (l + 64) * 4);
      eb[du][0] = a.enc_bi[u] + a.enc_bh[u];
      eb[du][1] = a.enc_bi[512 + u] + a.enc_bh[512 + u];
      eb[du][2] = a.enc_bi[1024 + u];
      eb[du][3] = a.enc_bh[1024 + u];
    }
    asm volatile("" ::: "memory");   // pin weight values in registers (no re-load)
#pragma unroll 1
    for (int t = 0; t < 64; ++t) {
      const float* hin = hbuf[t & 1];
      float* hout = hbuf[(t + 1) & 1];
      for (int idx = tid; idx < 16 * 192; idx += NTHR) {   // x = [dense_t(256)|h(512)]
        int bl = idx / 192, kk = idx - bl * 192;
        float4 v = (kk < 64)
            ? *(const float4*)&dense[((b0x + bl) * 64 + t) * 256 + kk * 4]
            : *(const float4*)&hin[(b0x + bl) * 512 + (kk - 64) * 4];
        *(float4*)&sm.e.xs[bl * 768 + kk * 4] = v;
      }
      __syncthreads();
#pragma unroll 2
      for (int b = 0; b < 16; ++b) {
        const float* xr = sm.e.xs + b * 768;
        float4 xv0 = *(const float4*)(xr + l * 4);
        float4 xv1 = *(const float4*)(xr + 256 + l * 4);
        float4 xv2 = *(const float4*)(xr + 512 + l * 4);
        float aR0 = dot4(ewr[0][0], xv0) + dot4(ewr[0][1], xv1) + dot4(ewr[0][2], xv2);
        float aZ0 = dot4(ewz[0][0], xv0) + dot4(ewz[0][1], xv1) + dot4(ewz[0][2], xv2);
        float aI0 = dot4(ewin[0], xv0);
        float aH0 = dot4(ewhn[0][0], xv1) + dot4(ewhn[0][1], xv2);
        float aR1 = dot4(ewr[1][0], xv0) + dot4(ewr[1][1], xv1) + dot4(ewr[1][2], xv2);
        float aZ1 = dot4(ewz[1][0], xv0) + dot4(ewz[1][1], xv1) + dot4(ewz[1][2], xv2);
        float aI1 = dot4(ewin[1], xv0);
        float aH1 = dot4(ewhn[1][0], xv1) + dot4(ewhn[1][1], xv2);
        aR0 = wsum(aR0); aZ0 = wsum(aZ0); aI0 = wsum(aI0); aH0 = wsum(aH0);
        aR1 = wsum(aR1); aZ1 = wsum(aZ1); aI1 = wsum(aI1); aH1 = wsum(aH1);
        const int gb = b0x + b;
        float r0 = sigmoidf_(aR0 + eb[0][0]);
        float z0 = sigmoidf_(aZ0 + eb[0][1]);
        float n0 = fast_tanh(aI0 + eb[0][2] + r0 * (aH0 + eb[0][3]));
        float h0v = (1.f - z0) * n0 + z0 * xr[256 + ua];
        float r1 = sigmoidf_(aR1 + eb[1][0]);
        float z1 = sigmoidf_(aZ1 + eb[1][1]);
        float n1 = fast_tanh(aI1 + eb[1][2] + r1 * (aH1 + eb[1][3]));
        float h1v = (1.f - z1) * n1 + z1 * xr[256 + ua + 1];
        if (l == 0) {
          int lenb = a.lengths[gb];
          float2 hv = make_float2(h0v, h1v);
          *(float2*)&hout[gb * 512 + ua] = hv;
          float2 ev = (t < lenb) ? hv : make_float2(0.f, 0.f);
          *(float2*)&enc_out[(gb * 64 + t) * 512 + ua] = ev;
          if (t == lenb - 1) *(float2*)&h0buf[gb * 512 + ua] = hv;
        }
      }
      xbar(bar, xcd);
    }
  }

  // ---------------- EK: enc_keys (XCD-local) ----------------
#pragma unroll 1
  for (int rep = 0; rep < 2; ++rep) {
    const int r0 = xcd * 1024 + sid * 32 + rep * 16;
    for (int idx = tid; idx < 16 * 512; idx += NTHR) sm.ek.s[idx] = enc_out[r0 * 512 + idx];
    __syncthreads();
    float acc[16];
#pragma unroll
    for (int ri = 0; ri < 16; ++ri) acc[ri] = 0.f;
    for (int h = 0; h < 512; ++h) {
      float wv = a.s2s_Wk[h * 512 + tid];
#pragma unroll
      for (int ri = 0; ri < 16; ++ri) acc[ri] = fmaf(sm.ek.s[ri * 512 + h], wv, acc[ri]);
    }
#pragma unroll
    for (int ri = 0; ri < 16; ++ri) enc_keys[(r0 + ri) * 512 + tid] = acc[ri];
    __syncthreads();
  }
  xbar(bar, xcd);

  // ---------------- decoder persistent registers ----------------
  float4 dwr[2][5], dwz[2][5], dwin[2][3], dwhn[2][2];   // 120 VGPR gate weights
  float db[2][4];
#pragma unroll
  for (int du = 0; du < 2; ++du) {
    const int u = ua + du;
#pragma unroll
    for (int j = 0; j < 3; ++j) {
      dwr[du][j]  = *(const float4*)(a.dec_Wi + (u) * 768 + (l + 64 * j) * 4);
      dwz[du][j]  = *(const float4*)(a.dec_Wi + (512 + u) * 768 + (l + 64 * j) * 4);
      dwin[du][j] = *(const float4*)(a.dec_Wi + (1024 + u) * 768 + (l + 64 * j) * 4);
    }
    dwr[du][3] = *(const float4*)(a.dec_Wh + (u) * 512 + l * 4);
    dwr[du][4] = *(const float4*)(a.dec_Wh + (u) * 512 + (l + 64) * 4);
    dwz[du][3] = *(const float4*)(a.dec_Wh + (512 + u) * 512 + l * 4);
    dwz[du][4] = *(const float4*)(a.dec_Wh + (512 + u) * 512 + (l + 64) * 4);
    dwhn[du][0] = *(const float4*)(a.dec_Wh + (1024 + u) * 512 + l * 4);
    dwhn[du][1] = *(const float4*)(a.dec_Wh + (1024 + u) * 512 + (l + 64) * 4);
    db[du][0] = a.dec_bi[u] + a.dec_bh[u];
    db[du][1] = a.dec_bi[512 + u] + a.dec_bh[512 + u];
    db[du][2] = a.dec_bi[1024 + u];
    db[du][3] = a.dec_bh[1024 + u];
  }
  // kr union: s2s blocks = enc_out column h=tid (context); ptr blocks =
  // register-hoisted ptr_keys (kr[li*4+c]). Shares one 64-reg allocation.
  float kr[64];
  if (sid < 16) {
    const int b = b0x + sid;
#pragma unroll
    for (int l2 = 0; l2 < 64; ++l2) kr[l2] = enc_out[(b * 64 + l2) * 512 + tid];
  } else {
    const int b = b0x + (sid - 16);
#pragma unroll
    for (int li = 0; li < 8; ++li)
#pragma unroll
      for (int c = 0; c < 4; ++c)
        kr[li * 4 + c] = ptr_keys[(b * 64 + w * 8 + li) * 256 + c * 64 + l];
#pragma unroll
    for (int l2 = 32; l2 < 64; ++l2) kr[l2] = 0.f;
  }
  asm volatile("" ::: "memory");   // pin persistent values in registers

  // A1-s2s: q-GEMV + attention + context -> xbuf (blocks sid<16)
  auto s2sphase = [&](int i, const float* hsrc) {
    const int b = b0x + sid;
    sm.p1.sh[tid] = hsrc[b * 512 + tid];
    __syncthreads();
    {
      float acc = 0.f;
#pragma unroll 4
      for (int k = 0; k < 512; k += 4) {
        float4 hv = *(const float4*)(sm.p1.sh + k);
        acc = fmaf(a.s2s_Wq[(k) * 512 + tid], hv.x,
              fmaf(a.s2s_Wq[(k + 1) * 512 + tid], hv.y,
              fmaf(a.s2s_Wq[(k + 2) * 512 + tid], hv.z,
              fmaf(a.s2s_Wq[(k + 3) * 512 + tid], hv.w, acc))));
      }
      sm.p1.qq[tid] = acc;
    }
    __syncthreads();
    const int lenb = a.lengths[b];
    float rq[8], sv[8];
#pragma unroll
    for (int c = 0; c < 8; ++c) { rq[c] = sm.p1.qq[c * 64 + l]; sv[c] = a.s2s_v[c * 64 + l]; }
#pragma unroll
    for (int li = 0; li < 8; ++li) {
      int lr = w * 8 + li;
      float acc = 0.f;
#pragma unroll
      for (int c = 0; c < 8; ++c)
        acc = fmaf(fast_tanh(rq[c] + enc_keys[(b * 64 + lr) * 512 + c * 64 + l]), sv[c], acc);
      acc = wsum(acc);
      if (l == 0) sm.p1.sl[lr] = ((i < lenb) && (lr < lenb)) ? acc : NEGC;
    }
    __syncthreads();
    if (tid < 64) {
      float v = sm.p1.sl[tid];
      float m = v;
#pragma unroll
      for (int off = 32; off > 0; off >>= 1) m = fmaxf(m, __shfl_xor(m, off));
      float e = __expf(v - m);
      float s = e;
#pragma unroll
      for (int off = 32; off > 0; off >>= 1) s += __shfl_xor(s, off);
      sm.p1.wl[tid] = e / s;
    }
    __syncthreads();
    {
      float c = 0.f;
#pragma unroll
      for (int l2 = 0; l2 < 64; ++l2) c = fmaf(sm.p1.wl[l2], kr[l2], c);
      xbuf[b * 768 + tid] = c;
    }
    if (tid < 256) {
      int di = (i == 0) ? 0 : a.targets[b * 64 + i - 1];
      xbuf[b * 768 + 512 + tid] = dense[(b * 64 + di) * 256 + tid];
    }
  };

  // A1-ptr: pq-GEMV + pointer logits j=i-1 (blocks sid>=16); keys in kr[0..31]
  auto ptrphase = [&](int i, const float* hsrc) {
    if (i == 0) return;
    const int b = b0x + (sid - 16);
    sm.p1.sh[tid] = hsrc[b * 512 + tid];
    __syncthreads();
    {
      const int o = tid & 255, hf = tid >> 8;
      float acc = 0.f;
      const int k0 = hf * 256;
#pragma unroll 4
      for (int k = k0; k < k0 + 256; k += 4) {
        float4 hv = *(const float4*)(sm.p1.sh + k);
        acc = fmaf(Mt2[(k) * 256 + o], hv.x,
              fmaf(Mt2[(k + 1) * 256 + o], hv.y,
              fmaf(Mt2[(k + 2) * 256 + o], hv.z,
              fmaf(Mt2[(k + 3) * 256 + o], hv.w, acc))));
      }
      sm.p1.pp[hf * 256 + o] = acc;
    }
    __syncthreads();
    if (tid < 256) sm.p1.qq[tid] = sm.p1.pp[tid] + sm.p1.pp[256 + tid] + bqv[tid];
    __syncthreads();
    const int j = i - 1;
    const int lenb = a.lengths[b];
    float rq[4], pv[4];
#pragma unroll
    for (int c = 0; c < 4; ++c) { rq[c] = sm.p1.qq[c * 64 + l]; pv[c] = a.ptr_v[c * 64 + l]; }
#pragma unroll
    for (int li = 0; li < 8; ++li) {
      int lr = w * 8 + li;
      float acc = 0.f;
#pragma unroll
      for (int c = 0; c < 4; ++c)
        acc = fmaf(fast_tanh(rq[c] + kr[li * 4 + c]), pv[c], acc);
      acc = wsum(acc);
      if (l == 0) sm.p1.sl[lr] = acc;
    }
    __syncthreads();
    if (tid < 64) {
      int lr = tid;
      bool pm = (j < lenb) && (lr < lenb) && ((alive >> lr) & 1ull);
      float v = pm ? sm.p1.sl[lr] : NEGC;
      a.logits[(b * 64 + j) * 64 + lr] = v;
      float bv = v; int bidx = lr;
#pragma unroll
      for (int off = 32; off > 0; off >>= 1) {
        float ov = __shfl_xor(bv, off);
        int oi = __shfl_xor(bidx, off);
        if (ov > bv || (ov == bv && oi < bidx)) { bv = ov; bidx = oi; }
      }
      if (lr == 0) a.preds[b * 64 + j] = (float)bidx;
    }
    alive &= ~(1ull << (unsigned)a.targets[b * 64 + j]);
    __syncthreads();
  };

  // ---------------- decoder: 64 x { P1(s2s || ptr), P2(gates) } ----------------
#pragma unroll 1
  for (int i = 0; i < 64; ++i) {
    const float* hsrc = (i == 0) ? h0buf : hbuf[i & 1];
    if (sid < 16) s2sphase(i, hsrc); else ptrphase(i, hsrc);
    xbar(bar, xcd);
    {   // P2: register-weight gates, x = [xbuf(768)|h(512)]
      const float* hin = hsrc;
      for (int idx = tid; idx < 16 * 320; idx += NTHR) {
        int bl = idx / 320, kk = idx - bl * 320;
        float4 v = (kk < 192) ? *(const float4*)&xbuf[(b0x + bl) * 768 + kk * 4]
                              : *(const float4*)&hin[(b0x + bl) * 512 + (kk - 192) * 4];
        *(float4*)&sm.p2.xs[bl * 1280 + kk * 4] = v;
      }
      __syncthreads();
#pragma unroll 2
      for (int b = 0; b < 16; ++b) {
        const float* xr = sm.p2.xs + b * 1280;
        float4 xv0 = *(const float4*)(xr + l * 4);
        float4 xv1 = *(const float4*)(xr + 256 + l * 4);
        float4 xv2 = *(const float4*)(xr + 512 + l * 4);
        float4 xv3 = *(const float4*)(xr + 768 + l * 4);
        float4 xv4 = *(const float4*)(xr + 1024 + l * 4);
        float aR0 = dot4(dwr[0][0], xv0) + dot4(dwr[0][1], xv1) + dot4(dwr[0][2], xv2)
                  + dot4(dwr[0][3], xv3) + dot4(dwr[0][4], xv4);
        float aZ0 = dot4(dwz[0][0], xv0) + dot4(dwz[0][1], xv1) + dot4(dwz[0][2], xv2)
                  + dot4(dwz[0][3], xv3) + dot4(dwz[0][4], xv4);
        float aI0 = dot4(dwin[0][0], xv0) + dot4(dwin[0][1], xv1) + dot4(dwin[0][2], xv2);
        float aH0 = dot4(dwhn[0][0], xv3) + dot4(dwhn[0][1], xv4);
        float aR1 = dot4(dwr[1][0], xv0) + dot4(dwr[1][1], xv1) + dot4(dwr[1][2], xv2)
                  + dot4(dwr[1][3], xv3) + dot4(dwr[1][4], xv4);
        float aZ1 = dot4(dwz[1][0], xv0) + dot4(dwz[1][1], xv1) + dot4(dwz[1][2], xv2)
                  + dot4(dwz[1][3], xv3) + dot4(dwz[1][4], xv4);
        float aI1 = dot4(dwin[1][0], xv0) + dot4(dwin[1][1], xv1) + dot4(dwin[1][2], xv2);
        float aH1 = dot4(dwhn[1][0], xv3) + dot4(dwhn[1][1], xv4);
        aR0 = wsum(aR0); aZ0 = wsum(aZ0); aI0 = wsum(aI0); aH0 = wsum(aH0);
        aR1 = wsum(aR1); aZ1 = wsum(aZ1); aI1 = wsum(aI1); aH1 = wsum(aH1);
        float r0 = sigmoidf_(aR0 + db[0][0]);
        float z0 = sigmoidf_(aZ0 + db[0][1]);
        float n0 = fast_tanh(aI0 + db[0][2] + r0 * (aH0 + db[0][3]));
        float hv0 = (1.f - z0) * n0 + z0 * xr[768 + ua];
        float r1 = sigmoidf_(aR1 + db[1][0]);
        float z1 = sigmoidf_(aZ1 + db[1][1]);
        float n1 = fast_tanh(aI1 + db[1][2] + r1 * (aH1 + db[1][3]));
        float hv1 = (1.f - z1) * n1 + z1 * xr[768 + ua + 1];
        if (l == 0)
          *(float2*)&hbuf[(i + 1) & 1][(b0x + b) * 512 + ua] = make_float2(hv0, hv1);
      }
    }
    xbar(bar, xcd);
  }
  if (sid >= 16) ptrphase(64, hbuf[0]);   // final pointer row j=63 (h_64 in hbuf[0])
}

extern "C" void kernel_launch(void* const* d_in, const int* in_sizes, int n_in,
                              void* d_out, int out_size, void* d_ws, size_t ws_size,
                              hipStream_t stream) {
  (void)in_sizes; (void)n_in; (void)out_size; (void)ws_size;
  MegaArgs ma;
  ma.inputs  = (const float*)d_in[0];
  ma.lengths = (const int*)d_in[1];
  ma.targets = (const int*)d_in[2];
  ma.W_in    = (const float*)d_in[3];
  ma.b_in    = (const float*)d_in[4];
  ma.enc_Wi  = (const float*)d_in[5];
  ma.enc_Wh  = (const float*)d_in[6];
  ma.enc_bi  = (const float*)d_in[7];
  ma.enc_bh  = (const float*)d_in[8];
  ma.dec_Wi  = (const float*)d_in[9];
  ma.dec_Wh  = (const float*)d_in[10];
  ma.dec_bi  = (const float*)d_in[11];
  ma.dec_bh  = (const float*)d_in[12];
  ma.s2s_Wq  = (const float*)d_in[13];
  ma.s2s_Wk  = (const float*)d_in[14];
  ma.s2s_v   = (const float*)d_in[15];
  ma.W_out   = (const float*)d_in[16];
  ma.b_out   = (const float*)d_in[17];
  ma.ptr_Wq  = (const float*)d_in[18];
  ma.ptr_Wk  = (const float*)d_in[19];
  ma.ptr_v   = (const float*)d_in[20];
  ma.ws     = (float*)d_ws;
  ma.logits = (float*)d_out;
  ma.preds  = (float*)d_out + BB * LL * LL;

  hipMemsetAsync((float*)d_ws + OFF_BAR, 0, 8192, stream);

  void* kp[] = { &ma };
  hipLaunchCooperativeKernel(reinterpret_cast<const void*>(&mega),
                             dim3(NBLK), dim3(NTHR), kp, 0, stream);
}

// Round 10
// 8403.607 us; speedup vs baseline: 1.0353x; 1.0098x over previous
//
#include <hip/hip_runtime.h>

// Problem dims
#define BB 128
#define LL 64
#define DD 256
#define HH 512
#define NEGC (-1e9f)

// Persistent grid: 256 blocks x 512 threads, 1 block/CU (82KB LDS forces it).
// XCD x (physical, via HW_REG_XCC_ID + slot claim) owns batches [16x,16x+16).
// R10 = R9 resubmission (R9 hit an infra container failure, never measured).
// Single variable vs R8: XCD-local barrier is a store-slot + parallel-poll
// barrier (no contended fetch_add RMW):
//   - arriving block stores its epoch to a private 64B-spaced slot (no RMW)
//   - leader block polls all 31 slots in PARALLEL (lanes 1..31 of wave 0)
//   - leader stores gen=ep; waiters poll gen. Epochs monotone, replay-safe.
#define NBLK 256
#define NTHR 512

// ws offsets (floats)
#define OFF_DENSE   0            // B*L*D
#define OFF_ENCOUT  2097152      // B*L*H
#define OFF_ENCKEYS 6291456      // B*L*512
#define OFF_PTRKEYS 10485760     // B*L*256
#define OFF_X       12582912     // B*768 [ctx|dec_in]
#define OFF_HB0     12681216     // B*H
#define OFF_HB1     12746752     // B*H
#define OFF_H0      12812288     // B*H
#define OFF_MT      13238272     // Mt2[h=512][a=256] = (W_out^T @ ptr_Wq)
#define OFF_BQ      13369344     // 256
#define OFF_BAR     13369600     // uints: heavybar leaf@32i,root@512,gen@544;
                                 // claim@896+8x; xcd gen@768+8x;
                                 // slots@1024 + xcd*512 + sid*16 (64B spacing)

__device__ __forceinline__ float fast_tanh(float x) {
  float e = __expf(2.0f * x);
  return 1.0f - 2.0f / (e + 1.0f);
}
__device__ __forceinline__ float sigmoidf_(float x) {
  return 1.0f / (1.0f + __expf(-x));
}
__device__ __forceinline__ float wsum(float v) {
#pragma unroll
  for (int o = 32; o > 0; o >>= 1) v += __shfl_xor(v, o);
  return v;
}
__device__ __forceinline__ float dot4(float4 a, float4 b) {
  return fmaf(a.x, b.x, fmaf(a.y, b.y, fmaf(a.z, b.z, a.w * b.w)));
}

struct MegaArgs {
  const float* inputs; const int* lengths; const int* targets;
  const float* W_in; const float* b_in;
  const float* enc_Wi; const float* enc_Wh; const float* enc_bi; const float* enc_bh;
  const float* dec_Wi; const float* dec_Wh; const float* dec_bi; const float* dec_bh;
  const float* s2s_Wq; const float* s2s_Wk; const float* s2s_v;
  const float* W_out; const float* b_out;
  const float* ptr_Wq; const float* ptr_Wk; const float* ptr_v;
  float* ws; float* logits; float* preds;
};

// XCD-local barrier, store-slot + parallel-poll (no RMW contention).
// Data correctness (R5-R8-proven model): writers' __syncthreads drains vmcnt
// -> stores visible in the XCD's shared L2; readers refetch after the
// vL1-only buffer_inv. Slot/gen traffic uses relaxed agent-scope atomics
// (sc0 sc1, coherent-point) -- no cache-wide invalidation.
__device__ __forceinline__ void xbar(unsigned* bar, int xcd, int sid, unsigned ep) {
  __syncthreads();
  const int tid = threadIdx.x;
  unsigned* slots = bar + 1024 + xcd * 512;      // 32 slots x 16 uints (64B apart)
  unsigned* gen   = bar + 768 + xcd * 8;
  if (sid == 0) {
    // leader: lanes 1..31 of wave 0 each poll one slot in parallel
    if (tid >= 1 && tid < 32) {
      while (__hip_atomic_load(slots + tid * 16, __ATOMIC_RELAXED,
                               __HIP_MEMORY_SCOPE_AGENT) < ep)
        __builtin_amdgcn_s_sleep(1);
    }
    __syncthreads();   // all slots seen >= ep
    if (tid == 0)
      __hip_atomic_store(gen, ep, __ATOMIC_RELAXED, __HIP_MEMORY_SCOPE_AGENT);
  } else {
    if (tid == 0) {
      __hip_atomic_store(slots + sid * 16, ep, __ATOMIC_RELAXED,
                         __HIP_MEMORY_SCOPE_AGENT);
      while (__hip_atomic_load(gen, __ATOMIC_RELAXED,
                               __HIP_MEMORY_SCOPE_AGENT) < ep)
        __builtin_amdgcn_s_sleep(1);
    }
  }
  if (tid == 0) asm volatile("buffer_inv" ::: "memory");   // vL1-only, cheap
  __syncthreads();
}

// Grid-wide heavy barrier (used once post-setup): full fence pair.
__device__ __forceinline__ void heavybar(unsigned* bar, int blk) {
  __syncthreads();
  if (threadIdx.x == 0) {
    __threadfence();
    unsigned* leaf = bar + ((blk >> 4) << 5);
    unsigned* root = bar + 512;
    unsigned* gen  = bar + 544;
    unsigned g = __hip_atomic_load(gen, __ATOMIC_RELAXED, __HIP_MEMORY_SCOPE_AGENT);
    unsigned v = __hip_atomic_fetch_add(leaf, 1u, __ATOMIC_RELAXED, __HIP_MEMORY_SCOPE_AGENT);
    if ((v & 15u) == 15u) {
      unsigned r = __hip_atomic_fetch_add(root, 1u, __ATOMIC_RELAXED, __HIP_MEMORY_SCOPE_AGENT);
      if ((r & 15u) == 15u)
        __hip_atomic_store(gen, g + 1u, __ATOMIC_RELAXED, __HIP_MEMORY_SCOPE_AGENT);
    }
    while (__hip_atomic_load(gen, __ATOMIC_RELAXED, __HIP_MEMORY_SCOPE_AGENT) == g)
      __builtin_amdgcn_s_sleep(1);
    __threadfence();
  }
  __syncthreads();
}

struct SMem {
  union {
    struct { float xs[16 * 768]; } e;                                  // encoder x [dense|h]
    struct { float xs[16 * 1280]; } p2;                                // dec x [xbuf|h] 80KB
    struct { float sh[512]; float qq[768]; float pp[512]; float sl[64]; float wl[64]; } p1;
    struct { float s[32 * 256]; } pk;
    struct { float s[16 * 512]; } ek;
  };
  float pad_[160];    // push LDS >80KB -> exactly 1 block/CU
  unsigned xcd, sid;
};

__global__ __launch_bounds__(NTHR, 1) void mega(MegaArgs a) {
  const int blk = blockIdx.x;
  const int tid = threadIdx.x;
  float* ws = a.ws;
  float* dense    = ws + OFF_DENSE;
  float* enc_out  = ws + OFF_ENCOUT;
  float* enc_keys = ws + OFF_ENCKEYS;
  float* ptr_keys = ws + OFF_PTRKEYS;
  float* xbuf     = ws + OFF_X;
  float* hbuf[2]  = { ws + OFF_HB0, ws + OFF_HB1 };
  float* h0buf    = ws + OFF_H0;
  float* Mt2      = ws + OFF_MT;
  float* bqv      = ws + OFF_BQ;
  unsigned* bar   = (unsigned*)(ws + OFF_BAR);

  __shared__ SMem sm;

  // ---- physical XCD + slot claim (R5-proven) ----
  if (tid == 0) {
    unsigned x;
    asm volatile("s_getreg_b32 %0, hwreg(HW_REG_XCC_ID)" : "=s"(x));
    x &= 7u;
    unsigned s = __hip_atomic_fetch_add(bar + 896 + x * 8, 1u,
                                        __ATOMIC_RELAXED, __HIP_MEMORY_SCOPE_AGENT);
    sm.xcd = x; sm.sid = s & 31u;
  }
  __syncthreads();
  const int xcd = sm.xcd, sid = sm.sid;
  const int b0x = xcd * 16;
  const int w = tid >> 6, l = tid & 63;
  const int u0 = sid * 16;
  const int ua = u0 + 2 * w;          // this wave's unit pair (ua, ua+1)

  unsigned long long alive = ~0ull;   // pointer mask (pointer blocks, sid>=16)
  unsigned ep = 0;                    // XCD-barrier epoch (identical on all blocks)

  // ---------------- S1: dense (local), Mt2/bqv (global), zero hb0 ----------------
  for (int idx = sid * NTHR + tid; idx < 16 * 64 * 256; idx += 32 * NTHR) {
    int row = idx >> 8, d = idx & 255;
    int g = b0x * 64 + row;
    dense[g * 256 + d] = fmaf(a.inputs[g * 2], a.W_in[d * 2],
                         fmaf(a.inputs[g * 2 + 1], a.W_in[d * 2 + 1], a.b_in[d]));
  }
  if (tid < 256) {   // Mt2 rows 2blk, 2blk+1
    int h1 = blk * 2;
    float acc1 = 0.f, acc2 = 0.f;
    for (int d = 0; d < 256; ++d) {
      float p = a.ptr_Wq[d * 256 + tid];
      acc1 = fmaf(a.W_out[d * 512 + h1], p, acc1);
      acc2 = fmaf(a.W_out[d * 512 + h1 + 1], p, acc2);
    }
    Mt2[h1 * 256 + tid] = acc1;
    Mt2[(h1 + 1) * 256 + tid] = acc2;
  }
  if (blk == 0 && tid < 256) {
    float acc = 0.f;
    for (int d = 0; d < 256; ++d) acc = fmaf(a.b_out[d], a.ptr_Wq[d * 256 + tid], acc);
    bqv[tid] = acc;
  }
  for (int idx = sid * NTHR + tid; idx < 16 * 512; idx += 32 * NTHR)
    hbuf[0][b0x * 512 + idx] = 0.f;
  heavybar(bar, blk);

  // ---------------- PK: ptr_keys (XCD-local, 32 rows/block) ----------------
  {
    const int r0 = xcd * 1024 + sid * 32;
    for (int idx = tid; idx < 32 * 256; idx += NTHR) sm.pk.s[idx] = dense[r0 * 256 + idx];
    __syncthreads();
    const int col = tid & 255, rg = tid >> 8;
    float acc[16];
#pragma unroll
    for (int ri = 0; ri < 16; ++ri) acc[ri] = 0.f;
    const float* srow = sm.pk.s + rg * 16 * 256;
    for (int d = 0; d < 256; ++d) {
      float wv = a.ptr_Wk[d * 256 + col];
#pragma unroll
      for (int ri = 0; ri < 16; ++ri) acc[ri] = fmaf(srow[ri * 256 + d], wv, acc[ri]);
    }
#pragma unroll
    for (int ri = 0; ri < 16; ++ri)
      ptr_keys[(r0 + rg * 16 + ri) * 256 + col] = acc[ri];
  }
  xbar(bar, xcd, sid, ++ep);

  // ---------------- encoder: register-stationary weights ----------------
  {
    float4 ewr[2][3], ewz[2][3], ewin[2], ewhn[2][2];
    float eb[2][4];
#pragma unroll
    for (int du = 0; du < 2; ++du) {
      const int u = ua + du;
      ewr[du][0] = *(const float4*)(a.enc_Wi + (u) * 256 + l * 4);
      ewr[du][1] = *(const float4*)(a.enc_Wh + (u) * 512 + l * 4);
      ewr[du][2] = *(const float4*)(a.enc_Wh + (u) * 512 + (l + 64) * 4);
      ewz[du][0] = *(const float4*)(a.enc_Wi + (512 + u) * 256 + l * 4);
      ewz[du][1] = *(const float4*)(a.enc_Wh + (512 + u) * 512 + l * 4);
      ewz[du][2] = *(const float4*)(a.enc_Wh + (512 + u) * 512 + (l + 64) * 4);
      ewin[du]    = *(const float4*)(a.enc_Wi + (1024 + u) * 256 + l * 4);
      ewhn[du][0] = *(const float4*)(a.enc_Wh + (1024 + u) * 512 + l * 4);
      ewhn[du][1] = *(const float4*)(a.enc_Wh + (1024 + u) * 512 + (l + 64) * 4);
      eb[du][0] = a.enc_bi[u] + a.enc_bh[u];
      eb[du][1] = a.enc_bi[512 + u] + a.enc_bh[512 + u];
      eb[du][2] = a.enc_bi[1024 + u];
      eb[du][3] = a.enc_bh[1024 + u];
    }
    asm volatile("" ::: "memory");   // pin weight values in registers (no re-load)
#pragma unroll 1
    for (int t = 0; t < 64; ++t) {
      const float* hin = hbuf[t & 1];
      float* hout = hbuf[(t + 1) & 1];
      for (int idx = tid; idx < 16 * 192; idx += NTHR) {   // x = [dense_t(256)|h(512)]
        int bl = idx / 192, kk = idx - bl * 192;
        float4 v = (kk < 64)
            ? *(const float4*)&dense[((b0x + bl) * 64 + t) * 256 + kk * 4]
            : *(const float4*)&hin[(b0x + bl) * 512 + (kk - 64) * 4];
        *(float4*)&sm.e.xs[bl * 768 + kk * 4] = v;
      }
      __syncthreads();
#pragma unroll 2
      for (int b = 0; b < 16; ++b) {
        const float* xr = sm.e.xs + b * 768;
        float4 xv0 = *(const float4*)(xr + l * 4);
        float4 xv1 = *(const float4*)(xr + 256 + l * 4);
        float4 xv2 = *(const float4*)(xr + 512 + l * 4);
        float aR0 = dot4(ewr[0][0], xv0) + dot4(ewr[0][1], xv1) + dot4(ewr[0][2], xv2);
        float aZ0 = dot4(ewz[0][0], xv0) + dot4(ewz[0][1], xv1) + dot4(ewz[0][2], xv2);
        float aI0 = dot4(ewin[0], xv0);
        float aH0 = dot4(ewhn[0][0], xv1) + dot4(ewhn[0][1], xv2);
        float aR1 = dot4(ewr[1][0], xv0) + dot4(ewr[1][1], xv1) + dot4(ewr[1][2], xv2);
        float aZ1 = dot4(ewz[1][0], xv0) + dot4(ewz[1][1], xv1) + dot4(ewz[1][2], xv2);
        float aI1 = dot4(ewin[1], xv0);
        float aH1 = dot4(ewhn[1][0], xv1) + dot4(ewhn[1][1], xv2);
        aR0 = wsum(aR0); aZ0 = wsum(aZ0); aI0 = wsum(aI0); aH0 = wsum(aH0);
        aR1 = wsum(aR1); aZ1 = wsum(aZ1); aI1 = wsum(aI1); aH1 = wsum(aH1);
        const int gb = b0x + b;
        float r0 = sigmoidf_(aR0 + eb[0][0]);
        float z0 = sigmoidf_(aZ0 + eb[0][1]);
        float n0 = fast_tanh(aI0 + eb[0][2] + r0 * (aH0 + eb[0][3]));
        float h0v = (1.f - z0) * n0 + z0 * xr[256 + ua];
        float r1 = sigmoidf_(aR1 + eb[1][0]);
        float z1 = sigmoidf_(aZ1 + eb[1][1]);
        float n1 = fast_tanh(aI1 + eb[1][2] + r1 * (aH1 + eb[1][3]));
        float h1v = (1.f - z1) * n1 + z1 * xr[256 + ua + 1];
        if (l == 0) {
          int lenb = a.lengths[gb];
          float2 hv = make_float2(h0v, h1v);
          *(float2*)&hout[gb * 512 + ua] = hv;
          float2 ev = (t < lenb) ? hv : make_float2(0.f, 0.f);
          *(float2*)&enc_out[(gb * 64 + t) * 512 + ua] = ev;
          if (t == lenb - 1) *(float2*)&h0buf[gb * 512 + ua] = hv;
        }
      }
      xbar(bar, xcd, sid, ++ep);
    }
  }

  // ---------------- EK: enc_keys (XCD-local) ----------------
#pragma unroll 1
  for (int rep = 0; rep < 2; ++rep) {
    const int r0 = xcd * 1024 + sid * 32 + rep * 16;
    for (int idx = tid; idx < 16 * 512; idx += NTHR) sm.ek.s[idx] = enc_out[r0 * 512 + idx];
    __syncthreads();
    float acc[16];
#pragma unroll
    for (int ri = 0; ri < 16; ++ri) acc[ri] = 0.f;
    for (int h = 0; h < 512; ++h) {
      float wv = a.s2s_Wk[h * 512 + tid];
#pragma unroll
      for (int ri = 0; ri < 16; ++ri) acc[ri] = fmaf(sm.ek.s[ri * 512 + h], wv, acc[ri]);
    }
#pragma unroll
    for (int ri = 0; ri < 16; ++ri) enc_keys[(r0 + ri) * 512 + tid] = acc[ri];
    __syncthreads();
  }
  xbar(bar, xcd, sid, ++ep);

  // ---------------- decoder persistent registers ----------------
  float4 dwr[2][5], dwz[2][5], dwin[2][3], dwhn[2][2];   // 120 VGPR gate weights
  float db[2][4];
#pragma unroll
  for (int du = 0; du < 2; ++du) {
    const int u = ua + du;
#pragma unroll
    for (int j = 0; j < 3; ++j) {
      dwr[du][j]  = *(const float4*)(a.dec_Wi + (u) * 768 + (l + 64 * j) * 4);
      dwz[du][j]  = *(const float4*)(a.dec_Wi + (512 + u) * 768 + (l + 64 * j) * 4);
      dwin[du][j] = *(const float4*)(a.dec_Wi + (1024 + u) * 768 + (l + 64 * j) * 4);
    }
    dwr[du][3] = *(const float4*)(a.dec_Wh + (u) * 512 + l * 4);
    dwr[du][4] = *(const float4*)(a.dec_Wh + (u) * 512 + (l + 64) * 4);
    dwz[du][3] = *(const float4*)(a.dec_Wh + (512 + u) * 512 + l * 4);
    dwz[du][4] = *(const float4*)(a.dec_Wh + (512 + u) * 512 + (l + 64) * 4);
    dwhn[du][0] = *(const float4*)(a.dec_Wh + (1024 + u) * 512 + l * 4);
    dwhn[du][1] = *(const float4*)(a.dec_Wh + (1024 + u) * 512 + (l + 64) * 4);
    db[du][0] = a.dec_bi[u] + a.dec_bh[u];
    db[du][1] = a.dec_bi[512 + u] + a.dec_bh[512 + u];
    db[du][2] = a.dec_bi[1024 + u];
    db[du][3] = a.dec_bh[1024 + u];
  }
  // kr union: s2s blocks = enc_out column h=tid (context); ptr blocks =
  // register-hoisted ptr_keys (kr[li*4+c]). Shares one 64-reg allocation.
  float kr[64];
  if (sid < 16) {
    const int b = b0x + sid;
#pragma unroll
    for (int l2 = 0; l2 < 64; ++l2) kr[l2] = enc_out[(b * 64 + l2) * 512 + tid];
  } else {
    const int b = b0x + (sid - 16);
#pragma unroll
    for (int li = 0; li < 8; ++li)
#pragma unroll
      for (int c = 0; c < 4; ++c)
        kr[li * 4 + c] = ptr_keys[(b * 64 + w * 8 + li) * 256 + c * 64 + l];
#pragma unroll
    for (int l2 = 32; l2 < 64; ++l2) kr[l2] = 0.f;
  }
  asm volatile("" ::: "memory");   // pin persistent values in registers

  // A1-s2s: q-GEMV + attention + context -> xbuf (blocks sid<16)
  auto s2sphase = [&](int i, const float* hsrc) {
    const int b = b0x + sid;
    sm.p1.sh[tid] = hsrc[b * 512 + tid];
    __syncthreads();
    {
      float acc = 0.f;
#pragma unroll 4
      for (int k = 0; k < 512; k += 4) {
        float4 hv = *(const float4*)(sm.p1.sh + k);
        acc = fmaf(a.s2s_Wq[(k) * 512 + tid], hv.x,
              fmaf(a.s2s_Wq[(k + 1) * 512 + tid], hv.y,
              fmaf(a.s2s_Wq[(k + 2) * 512 + tid], hv.z,
              fmaf(a.s2s_Wq[(k + 3) * 512 + tid], hv.w, acc))));
      }
      sm.p1.qq[tid] = acc;
    }
    __syncthreads();
    const int lenb = a.lengths[b];
    float rq[8], sv[8];
#pragma unroll
    for (int c = 0; c < 8; ++c) { rq[c] = sm.p1.qq[c * 64 + l]; sv[c] = a.s2s_v[c * 64 + l]; }
#pragma unroll
    for (int li = 0; li < 8; ++li) {
      int lr = w * 8 + li;
      float acc = 0.f;
#pragma unroll
      for (int c = 0; c < 8; ++c)
        acc = fmaf(fast_tanh(rq[c] + enc_keys[(b * 64 + lr) * 512 + c * 64 + l]), sv[c], acc);
      acc = wsum(acc);
      if (l == 0) sm.p1.sl[lr] = ((i < lenb) && (lr < lenb)) ? acc : NEGC;
    }
    __syncthreads();
    if (tid < 64) {
      float v = sm.p1.sl[tid];
      float m = v;
#pragma unroll
      for (int off = 32; off > 0; off >>= 1) m = fmaxf(m, __shfl_xor(m, off));
      float e = __expf(v - m);
      float s = e;
#pragma unroll
      for (int off = 32; off > 0; off >>= 1) s += __shfl_xor(s, off);
      sm.p1.wl[tid] = e / s;
    }
    __syncthreads();
    {
      float c = 0.f;
#pragma unroll
      for (int l2 = 0; l2 < 64; ++l2) c = fmaf(sm.p1.wl[l2], kr[l2], c);
      xbuf[b * 768 + tid] = c;
    }
    if (tid < 256) {
      int di = (i == 0) ? 0 : a.targets[b * 64 + i - 1];
      xbuf[b * 768 + 512 + tid] = dense[(b * 64 + di) * 256 + tid];
    }
  };

  // A1-ptr: pq-GEMV + pointer logits j=i-1 (blocks sid>=16); keys in kr[0..31]
  auto ptrphase = [&](int i, const float* hsrc) {
    if (i == 0) return;
    const int b = b0x + (sid - 16);
    sm.p1.sh[tid] = hsrc[b * 512 + tid];
    __syncthreads();
    {
      const int o = tid & 255, hf = tid >> 8;
      float acc = 0.f;
      const int k0 = hf * 256;
#pragma unroll 4
      for (int k = k0; k < k0 + 256; k += 4) {
        float4 hv = *(const float4*)(sm.p1.sh + k);
        acc = fmaf(Mt2[(k) * 256 + o], hv.x,
              fmaf(Mt2[(k + 1) * 256 + o], hv.y,
              fmaf(Mt2[(k + 2) * 256 + o], hv.z,
              fmaf(Mt2[(k + 3) * 256 + o], hv.w, acc))));
      }
      sm.p1.pp[hf * 256 + o] = acc;
    }
    __syncthreads();
    if (tid < 256) sm.p1.qq[tid] = sm.p1.pp[tid] + sm.p1.pp[256 + tid] + bqv[tid];
    __syncthreads();
    const int j = i - 1;
    const int lenb = a.lengths[b];
    float rq[4], pv[4];
#pragma unroll
    for (int c = 0; c < 4; ++c) { rq[c] = sm.p1.qq[c * 64 + l]; pv[c] = a.ptr_v[c * 64 + l]; }
#pragma unroll
    for (int li = 0; li < 8; ++li) {
      int lr = w * 8 + li;
      float acc = 0.f;
#pragma unroll
      for (int c = 0; c < 4; ++c)
        acc = fmaf(fast_tanh(rq[c] + kr[li * 4 + c]), pv[c], acc);
      acc = wsum(acc);
      if (l == 0) sm.p1.sl[lr] = acc;
    }
    __syncthreads();
    if (tid < 64) {
      int lr = tid;
      bool pm = (j < lenb) && (lr < lenb) && ((alive >> lr) & 1ull);
      float v = pm ? sm.p1.sl[lr] : NEGC;
      a.logits[(b * 64 + j) * 64 + lr] = v;
      float bv = v; int bidx = lr;
#pragma unroll
      for (int off = 32; off > 0; off >>= 1) {
        float ov = __shfl_xor(bv, off);
        int oi = __shfl_xor(bidx, off);
        if (ov > bv || (ov == bv && oi < bidx)) { bv = ov; bidx = oi; }
      }
      if (lr == 0) a.preds[b * 64 + j] = (float)bidx;
    }
    alive &= ~(1ull << (unsigned)a.targets[b * 64 + j]);
    __syncthreads();
  };

  // ---------------- decoder: 64 x { P1(s2s || ptr), P2(gates) } ----------------
#pragma unroll 1
  for (int i = 0; i < 64; ++i) {
    const float* hsrc = (i == 0) ? h0buf : hbuf[i & 1];
    if (sid < 16) s2sphase(i, hsrc); else ptrphase(i, hsrc);
    xbar(bar, xcd, sid, ++ep);
    {   // P2: register-weight gates, x = [xbuf(768)|h(512)]
      const float* hin = hsrc;
      for (int idx = tid; idx < 16 * 320; idx += NTHR) {
        int bl = idx / 320, kk = idx - bl * 320;
        float4 v = (kk < 192) ? *(const float4*)&xbuf[(b0x + bl) * 768 + kk * 4]
                              : *(const float4*)&hin[(b0x + bl) * 512 + (kk - 192) * 4];
        *(float4*)&sm.p2.xs[bl * 1280 + kk * 4] = v;
      }
      __syncthreads();
#pragma unroll 2
      for (int b = 0; b < 16; ++b) {
        const float* xr = sm.p2.xs + b * 1280;
        float4 xv0 = *(const float4*)(xr + l * 4);
        float4 xv1 = *(const float4*)(xr + 256 + l * 4);
        float4 xv2 = *(const float4*)(xr + 512 + l * 4);
        float4 xv3 = *(const float4*)(xr + 768 + l * 4);
        float4 xv4 = *(const float4*)(xr + 1024 + l * 4);
        float aR0 = dot4(dwr[0][0], xv0) + dot4(dwr[0][1], xv1) + dot4(dwr[0][2], xv2)
                  + dot4(dwr[0][3], xv3) + dot4(dwr[0][4], xv4);
        float aZ0 = dot4(dwz[0][0], xv0) + dot4(dwz[0][1], xv1) + dot4(dwz[0][2], xv2)
                  + dot4(dwz[0][3], xv3) + dot4(dwz[0][4], xv4);
        float aI0 = dot4(dwin[0][0], xv0) + dot4(dwin[0][1], xv1) + dot4(dwin[0][2], xv2);
        float aH0 = dot4(dwhn[0][0], xv3) + dot4(dwhn[0][1], xv4);
        float aR1 = dot4(dwr[1][0], xv0) + dot4(dwr[1][1], xv1) + dot4(dwr[1][2], xv2)
                  + dot4(dwr[1][3], xv3) + dot4(dwr[1][4], xv4);
        float aZ1 = dot4(dwz[1][0], xv0) + dot4(dwz[1][1], xv1) + dot4(dwz[1][2], xv2)
                  + dot4(dwz[1][3], xv3) + dot4(dwz[1][4], xv4);
        float aI1 = dot4(dwin[1][0], xv0) + dot4(dwin[1][1], xv1) + dot4(dwin[1][2], xv2);
        float aH1 = dot4(dwhn[1][0], xv3) + dot4(dwhn[1][1], xv4);
        aR0 = wsum(aR0); aZ0 = wsum(aZ0); aI0 = wsum(aI0); aH0 = wsum(aH0);
        aR1 = wsum(aR1); aZ1 = wsum(aZ1); aI1 = wsum(aI1); aH1 = wsum(aH1);
        float r0 = sigmoidf_(aR0 + db[0][0]);
        float z0 = sigmoidf_(aZ0 + db[0][1]);
        float n0 = fast_tanh(aI0 + db[0][2] + r0 * (aH0 + db[0][3]));
        float hv0 = (1.f - z0) * n0 + z0 * xr[768 + ua];
        float r1 = sigmoidf_(aR1 + db[1][0]);
        float z1 = sigmoidf_(aZ1 + db[1][1]);
        float n1 = fast_tanh(aI1 + db[1][2] + r1 * (aH1 + db[1][3]));
        float hv1 = (1.f - z1) * n1 + z1 * xr[768 + ua + 1];
        if (l == 0)
          *(float2*)&hbuf[(i + 1) & 1][(b0x + b) * 512 + ua] = make_float2(hv0, hv1);
      }
    }
    xbar(bar, xcd, sid, ++ep);
  }
  if (sid >= 16) ptrphase(64, hbuf[0]);   // final pointer row j=63 (h_64 in hbuf[0])
}

extern "C" void kernel_launch(void* const* d_in, const int* in_sizes, int n_in,
                              void* d_out, int out_size, void* d_ws, size_t ws_size,
                              hipStream_t stream) {
  (void)in_sizes; (void)n_in; (void)out_size; (void)ws_size;
  MegaArgs ma;
  ma.inputs  = (const float*)d_in[0];
  ma.lengths = (const int*)d_in[1];
  ma.targets = (const int*)d_in[2];
  ma.W_in    = (const float*)d_in[3];
  ma.b_in    = (const float*)d_in[4];
  ma.enc_Wi  = (const float*)d_in[5];
  ma.enc_Wh  = (const float*)d_in[6];
  ma.enc_bi  = (const float*)d_in[7];
  ma.enc_bh  = (const float*)d_in[8];
  ma.dec_Wi  = (const float*)d_in[9];
  ma.dec_Wh  = (const float*)d_in[10];
  ma.dec_bi  = (const float*)d_in[11];
  ma.dec_bh  = (const float*)d_in[12];
  ma.s2s_Wq  = (const float*)d_in[13];
  ma.s2s_Wk  = (const float*)d_in[14];
  ma.s2s_v   = (const float*)d_in[15];
  ma.W_out   = (const float*)d_in[16];
  ma.b_out   = (const float*)d_in[17];
  ma.ptr_Wq  = (const float*)d_in[18];
  ma.ptr_Wk  = (const float*)d_in[19];
  ma.ptr_v   = (const float*)d_in[20];
  ma.ws     = (float*)d_ws;
  ma.logits = (float*)d_out;
  ma.preds  = (float*)d_out + BB * LL * LL;

  // zero heavybar + claim + xcd gens + slot region (20.5KB, within the 32KB tail)
  hipMemsetAsync((float*)d_ws + OFF_BAR, 0, 24576, stream);

  void* kp[] = { &ma };
  hipLaunchCooperativeKernel(reinterpret_cast<const void*>(&mega),
                             dim3(NBLK), dim3(NTHR), kp, 0, stream);
}